// Round 1
// baseline (6223.685 us; speedup 1.0000x reference)
//
#include <hip/hip_runtime.h>

#define TT 256
#define CONDL 192
#define PREDL 64
#define HH 256
#define BB 4096
#define BT 16            // batch tile per block
#define HPAD 264         // h row stride in bf16 elems (bank spread)
#define HBUF (BT * HPAD)

typedef short bf16x8 __attribute__((ext_vector_type(8)));
typedef float f32x4 __attribute__((ext_vector_type(4)));

__device__ __forceinline__ short f2bf(float f) {
  unsigned u = __builtin_bit_cast(unsigned, f);
  unsigned r = (u + 0x7fffu + ((u >> 16) & 1u)) >> 16;
  return (short)r;
}
__device__ __forceinline__ float bf2f(short s) {
  unsigned u = ((unsigned)(unsigned short)s) << 16;
  return __builtin_bit_cast(float, u);
}
__device__ __forceinline__ float sigmoidf_(float x) {
  return 1.0f / (1.0f + __expf(-x));
}
__device__ __forceinline__ float tanhf_(float x) {
  float e = __expf(2.0f * x);
  return 1.0f - 2.0f / (e + 1.0f);
}

// Pack w_hh [1024][256] fp32 -> bf16 B-fragments in exact MFMA operand order:
// frag (jt,kt): lane holds W[n = jt*16 + (lane&15)][k = kt*32 + (lane>>4)*8 + 0..7]
// flat layout: [(jt*8 + kt)*64 + lane] * 8 bf16  -> 16 B/lane, fully coalesced reads.
__global__ void pack_w(const float* __restrict__ w_hh, short* __restrict__ wp) {
  int idx = blockIdx.x * 256 + threadIdx.x;   // 0 .. 32767 = 64 jt * 8 kt * 64 lanes
  int lane = idx & 63;
  int kt = (idx >> 6) & 7;
  int jt = idx >> 9;
  int n = jt * 16 + (lane & 15);
  int k0 = kt * 32 + (lane >> 4) * 8;
  bf16x8 v;
#pragma unroll
  for (int j = 0; j < 8; ++j) v[j] = f2bf(w_hh[n * 256 + k0 + j]);
  *(bf16x8*)(wp + (long)idx * 8) = v;
}

__global__ __launch_bounds__(256, 1)
void lstm_main(const float* __restrict__ cd, const float* __restrict__ pred,
               const float* __restrict__ w_ih, const float* __restrict__ b_ih,
               const float* __restrict__ b_hh, const float* __restrict__ w_out,
               const float* __restrict__ b_out, const short* __restrict__ wp,
               float* __restrict__ out) {
  __shared__ __align__(16) short h_s[2 * HBUF];   // double-buffered bf16 hidden state
  __shared__ __align__(16) float x_s[TT * BT];    // time-major staged inputs

  const int tid = threadIdx.x;
  const int lane = tid & 63;
  const int wv = tid >> 6;        // wave 0..3
  const int r0 = blockIdx.x * BT; // batch row base
  const int lm = lane & 15;       // A-row / D-col index
  const int lq = lane >> 4;       // quad
  const int m0 = lq * 4;          // D-row base for this lane

  // stage x = concat(cd, pred) transposed to [t][r]  (MEAN=0, STD=1 -> no-op)
  for (int i = tid; i < BT * CONDL; i += 256) {
    int r = i / CONDL, t = i % CONDL;
    x_s[t * BT + r] = cd[(r0 + r) * CONDL + t];
  }
  for (int i = tid; i < BT * PREDL; i += 256) {
    int r = i / PREDL, t = i % PREDL;
    x_s[(CONDL + t) * BT + r] = pred[(r0 + r) * PREDL + t];
  }
  // h_0 = 0 in buffer 0
  for (int i = tid; i < HBUF; i += 256) h_s[i] = 0;

  // per-lane input-projection weight + fused biases for the 16 j-tiles this wave owns
  float wih_r[16], bsum_r[16];
#pragma unroll
  for (int a = 0; a < 16; ++a) {
    int j = (wv + 4 * a) * 16 + lm;
    wih_r[a] = w_ih[j];
    bsum_r[a] = b_ih[j] + b_hh[j];
  }

  float cst[16];   // fp32 cell state: 4 hidden groups (a) x 4 batch rows (v)
#pragma unroll
  for (int i = 0; i < 16; ++i) cst[i] = 0.f;

  const bf16x8* wpf = (const bf16x8*)wp;

  __syncthreads();

  for (int t = 0; t < TT; ++t) {
    const short* hr = h_s + (t & 1) * HBUF;
    short* hw = h_s + ((t + 1) & 1) * HBUF;

    // A-fragments of h_t: lane holds h[m=lm][k = kt*32 + lq*8 + 0..7]
    bf16x8 af[8];
#pragma unroll
    for (int kt = 0; kt < 8; ++kt)
      af[kt] = *(const bf16x8*)(hr + lm * HPAD + kt * 32 + lq * 8);

    // x_t for this lane's 4 batch rows
    f32x4 xv = *(const f32x4*)(x_s + t * BT + m0);

    f32x4 acc[16];
#pragma unroll
    for (int a = 0; a < 16; ++a) {
      int jt = wv + 4 * a;
      f32x4 cc;
      cc[0] = xv[0] * wih_r[a] + bsum_r[a];
      cc[1] = xv[1] * wih_r[a] + bsum_r[a];
      cc[2] = xv[2] * wih_r[a] + bsum_r[a];
      cc[3] = xv[3] * wih_r[a] + bsum_r[a];
#pragma unroll
      for (int kt = 0; kt < 8; ++kt) {
        cc = __builtin_amdgcn_mfma_f32_16x16x32_bf16(
            af[kt], wpf[(jt * 8 + kt) * 64 + lane], cc, 0, 0, 0);
      }
      acc[a] = cc;
    }

    // LSTM elementwise: wave wv owns hidden units u = (wv+4a)*16 + lm, a=0..3
#pragma unroll
    for (int a = 0; a < 4; ++a) {
      int u = (wv + 4 * a) * 16 + lm;
#pragma unroll
      for (int v = 0; v < 4; ++v) {
        float ig = sigmoidf_(acc[a][v]);
        float fg = sigmoidf_(acc[a + 4][v]);
        float gg = tanhf_(acc[a + 8][v]);
        float og = sigmoidf_(acc[a + 12][v]);
        float cn = fg * cst[a * 4 + v] + ig * gg;
        cst[a * 4 + v] = cn;
        hw[(m0 + v) * HPAD + u] = f2bf(og * tanhf_(cn));
      }
    }
    __syncthreads();
  }

  // readout: out[r] = sigmoid(h_last . w_out + b_out); h_last is in buffer 0 (T even)
  const short* hf = h_s;
  float bo = b_out[0];
#pragma unroll
  for (int rr = 0; rr < 4; ++rr) {
    int row = wv * 4 + rr;
    float p = 0.f;
#pragma unroll
    for (int c = 0; c < 4; ++c) {
      int k = lane + c * 64;
      p += bf2f(hf[row * HPAD + k]) * w_out[k];
    }
#pragma unroll
    for (int off = 32; off > 0; off >>= 1) p += __shfl_down(p, off);
    if (lane == 0) out[r0 + row] = sigmoidf_(p + bo);
  }
}

extern "C" void kernel_launch(void* const* d_in, const int* in_sizes, int n_in,
                              void* d_out, int out_size, void* d_ws, size_t ws_size,
                              hipStream_t stream) {
  const float* cd    = (const float*)d_in[0];
  const float* pr    = (const float*)d_in[1];
  const float* w_ih  = (const float*)d_in[2];
  const float* w_hh  = (const float*)d_in[3];
  const float* b_ih  = (const float*)d_in[4];
  const float* b_hh  = (const float*)d_in[5];
  const float* w_out = (const float*)d_in[6];
  const float* b_out = (const float*)d_in[7];
  float* out = (float*)d_out;
  short* wp = (short*)d_ws;   // 512 KB packed bf16 weights

  pack_w<<<128, 256, 0, stream>>>(w_hh, wp);
  lstm_main<<<256, 256, 0, stream>>>(cd, pr, w_ih, b_ih, b_hh, w_out, b_out, wp, out);
}

// Round 2
// 1028.361 us; speedup vs baseline: 6.0520x; 6.0520x over previous
//
#include <hip/hip_runtime.h>

#define TT 256
#define CONDL 192
#define PREDL 64
#define HH 256
#define BB 4096
#define BT 16            // batch tile per block
#define HPAD 264         // h row stride in bf16 elems (bank spread)
#define HBUF (BT * HPAD)

typedef short bf16x8 __attribute__((ext_vector_type(8)));
typedef float f32x4 __attribute__((ext_vector_type(4)));
typedef unsigned short u16x4 __attribute__((ext_vector_type(4)));

__device__ __forceinline__ short f2bf(float f) {
  unsigned u = __builtin_bit_cast(unsigned, f);
  unsigned r = (u + 0x7fffu + ((u >> 16) & 1u)) >> 16;
  return (short)r;
}
__device__ __forceinline__ float bf2f(short s) {
  unsigned u = ((unsigned)(unsigned short)s) << 16;
  return __builtin_bit_cast(float, u);
}
__device__ __forceinline__ float bflo(unsigned p) {
  return __builtin_bit_cast(float, p << 16);
}
__device__ __forceinline__ float bfhi(unsigned p) {
  return __builtin_bit_cast(float, p & 0xffff0000u);
}
__device__ __forceinline__ float sig_(float x) {
  // 1/(1+exp(-x)) via exp2 + rcp (graceful overflow: rcp(inf)=0)
  return __builtin_amdgcn_rcpf(1.0f + __builtin_amdgcn_exp2f(-1.44269504f * x));
}
__device__ __forceinline__ float tanh_(float x) {
  float e = __builtin_amdgcn_exp2f(2.88539008f * x);  // exp(2x)
  return 1.0f - 2.0f * __builtin_amdgcn_rcpf(e + 1.0f);
}

// Pack w_hh [1024][256] fp32 -> bf16 B-fragments in exact MFMA operand order:
// frag (jt,kt): lane holds W[n = jt*16 + (lane&15)][k = kt*32 + (lane>>4)*8 + 0..7]
__global__ void pack_w(const float* __restrict__ w_hh, short* __restrict__ wp) {
  int idx = blockIdx.x * 256 + threadIdx.x;   // 64 jt * 8 kt * 64 lanes
  int lane = idx & 63;
  int kt = (idx >> 6) & 7;
  int jt = idx >> 9;
  int n = jt * 16 + (lane & 15);
  int k0 = kt * 32 + (lane >> 4) * 8;
  bf16x8 v;
#pragma unroll
  for (int j = 0; j < 8; ++j) v[j] = f2bf(w_hh[n * 256 + k0 + j]);
  *(bf16x8*)(wp + (long)idx * 8) = v;
}

__global__ __launch_bounds__(256, 1)
void lstm_main(const float* __restrict__ cd, const float* __restrict__ pred,
               const float* __restrict__ w_ih, const float* __restrict__ b_ih,
               const float* __restrict__ b_hh, const float* __restrict__ w_out,
               const float* __restrict__ b_out, const short* __restrict__ wp,
               float* __restrict__ out) {
  // LDS budget: weights 128 KB + h dbuf 16.5 KB + x 8 KB = 152.5 KB (<160 KB)
  __shared__ __align__(16) short lds_w[16 * 8 * 64 * 8];  // 16 tiles, fragment order
  __shared__ __align__(16) short h_s[2 * HBUF];           // bf16 hidden, double-buffered
  __shared__ __align__(16) short x_s[TT * BT];            // bf16 inputs, time-major

  const int tid = threadIdx.x;
  const int lane = tid & 63;
  const int wv = tid >> 6;        // wave 0..3
  const int r0 = blockIdx.x * BT; // batch row base
  const int lm = lane & 15;
  const int lq = lane >> 4;
  const int m0 = lq * 4;

  const bf16x8* wpf = (const bf16x8*)wp;
  bf16x8* ldsw = (bf16x8*)lds_w;

  // ---- one-time staging ----
  // x = concat(cd, pred) -> bf16, time-major [t][r]
  for (int i = tid; i < BT * CONDL; i += 256) {
    int r = i / CONDL, t = i % CONDL;
    x_s[t * BT + r] = f2bf(cd[(r0 + r) * CONDL + t]);
  }
  for (int i = tid; i < BT * PREDL; i += 256) {
    int r = i / PREDL, t = i % PREDL;
    x_s[(CONDL + t) * BT + r] = f2bf(pred[(r0 + r) * PREDL + t]);
  }
  for (int i = tid; i < HBUF; i += 256) h_s[i] = 0;  // h_0 = 0, buffer 0

  // wave wv owns jt tiles {wv*4 + i + 16*g : i in 0..3, g in 0..3}
  // a index: a&3 = unit subtile i, a>>2 = gate g.  a<12 -> VGPR, a>=12 (o-gate) -> LDS.
  // LDS tiles: tile (wv*4+i) at frag index ((wv*4+i)*8+kt)*64+lane
#pragma unroll
  for (int i = 0; i < 4; ++i)
#pragma unroll
    for (int kt = 0; kt < 8; ++kt)
      ldsw[((wv * 4 + i) * 8 + kt) * 64 + lane] =
          wpf[((wv * 4 + i + 48) * 8 + kt) * 64 + lane];

  // VGPR-resident tiles: 12 per wave = 96 fragments = 384 VGPRs/lane
  bf16x8 wreg[96];
#pragma unroll
  for (int a = 0; a < 12; ++a)
#pragma unroll
    for (int kt = 0; kt < 8; ++kt)
      wreg[a * 8 + kt] = wpf[((wv * 4 + (a & 3) + 16 * (a >> 2)) * 8 + kt) * 64 + lane];
  // pin: prevent LLVM from rematerializing (re-loading) these per iteration
#pragma unroll
  for (int i = 0; i < 96; ++i) asm volatile("" : "+v"(wreg[i]));

  // packed (w_ih, b_ih+b_hh) per gate-row this lane owns: bf16 pair in one dword
  unsigned wbs[16];
#pragma unroll
  for (int a = 0; a < 16; ++a) {
    int j = (wv * 4 + (a & 3)) * 16 + lm + 256 * (a >> 2);
    unsigned lo = (unsigned short)f2bf(w_ih[j]);
    unsigned hi = (unsigned short)f2bf(b_ih[j] + b_hh[j]);
    wbs[a] = lo | (hi << 16);
  }

  float cst[16];
#pragma unroll
  for (int i = 0; i < 16; ++i) cst[i] = 0.f;

  f32x4 zero4;
  zero4[0] = 0.f; zero4[1] = 0.f; zero4[2] = 0.f; zero4[3] = 0.f;

  __syncthreads();

  // ---- recurrence ----
  for (int t = 0; t < TT; ++t) {
    const short* hr = h_s + (t & 1) * HBUF;
    short* hw = h_s + ((t + 1) & 1) * HBUF;

    f32x4 acc[16];
#pragma unroll
    for (int kt = 0; kt < 8; ++kt) {
      bf16x8 af = *(const bf16x8*)(hr + lm * HPAD + kt * 32 + lq * 8);
#pragma unroll
      for (int a = 0; a < 16; ++a) {
        bf16x8 wf = (a < 12) ? wreg[a * 8 + kt]
                             : ldsw[((wv * 4 + (a - 12)) * 8 + kt) * 64 + lane];
        acc[a] = __builtin_amdgcn_mfma_f32_16x16x32_bf16(
            af, wf, (kt == 0) ? zero4 : acc[a], 0, 0, 0);
      }
    }

    // x_t for this lane's 4 batch rows (one 8B LDS read)
    u16x4 xq = *(const u16x4*)(x_s + t * BT + m0);
    float xr[4];
#pragma unroll
    for (int v = 0; v < 4; ++v) xr[v] = bf2f((short)xq[v]);

    // LSTM elementwise; unit u = (wv*4+i)*16 + lm
#pragma unroll
    for (int i = 0; i < 4; ++i) {
      int u = (wv * 4 + i) * 16 + lm;
      float wI = bflo(wbs[i]),      bI = bfhi(wbs[i]);
      float wF = bflo(wbs[i + 4]),  bF = bfhi(wbs[i + 4]);
      float wG = bflo(wbs[i + 8]),  bG = bfhi(wbs[i + 8]);
      float wO = bflo(wbs[i + 12]), bO = bfhi(wbs[i + 12]);
#pragma unroll
      for (int v = 0; v < 4; ++v) {
        float ig = sig_(acc[i][v]      + xr[v] * wI + bI);
        float fg = sig_(acc[i + 4][v]  + xr[v] * wF + bF);
        float gg = tanh_(acc[i + 8][v] + xr[v] * wG + bG);
        float og = sig_(acc[i + 12][v] + xr[v] * wO + bO);
        float cn = fg * cst[i * 4 + v] + ig * gg;
        cst[i * 4 + v] = cn;
        hw[(m0 + v) * HPAD + u] = f2bf(og * tanh_(cn));
      }
    }
    __syncthreads();
  }

  // ---- readout: out[r] = sigmoid(h_last . w_out + b_out); buffer 0 (T even) ----
  const short* hf = h_s;
  float bo = b_out[0];
#pragma unroll
  for (int rr = 0; rr < 4; ++rr) {
    int row = wv * 4 + rr;
    float p = 0.f;
#pragma unroll
    for (int c = 0; c < 4; ++c) {
      int k = lane + c * 64;
      p += bf2f(hf[row * HPAD + k]) * w_out[k];
    }
#pragma unroll
    for (int off = 32; off > 0; off >>= 1) p += __shfl_down(p, off);
    if (lane == 0) out[r0 + row] = sig_(p + bo);
  }
}

extern "C" void kernel_launch(void* const* d_in, const int* in_sizes, int n_in,
                              void* d_out, int out_size, void* d_ws, size_t ws_size,
                              hipStream_t stream) {
  const float* cd    = (const float*)d_in[0];
  const float* pr    = (const float*)d_in[1];
  const float* w_ih  = (const float*)d_in[2];
  const float* w_hh  = (const float*)d_in[3];
  const float* b_ih  = (const float*)d_in[4];
  const float* b_hh  = (const float*)d_in[5];
  const float* w_out = (const float*)d_in[6];
  const float* b_out = (const float*)d_in[7];
  float* out = (float*)d_out;
  short* wp = (short*)d_ws;   // 512 KB packed bf16 weights

  pack_w<<<128, 256, 0, stream>>>(w_hh, wp);
  lstm_main<<<256, 256, 0, stream>>>(cd, pr, w_ih, b_ih, b_hh, w_out, b_out, wp, out);
}

// Round 3
// 766.860 us; speedup vs baseline: 8.1158x; 1.3410x over previous
//
#include <hip/hip_runtime.h>

#define TT 256
#define CONDL 192
#define PREDL 64
#define HH 256
#define BB 4096
#define BT 16            // batch tile per block
#define HPAD 264         // h row stride in bf16 elems (bank spread)
#define HBUF (BT * HPAD)
#define NTHR 512         // 8 waves, 2 per SIMD

typedef short bf16x8 __attribute__((ext_vector_type(8)));
typedef float f32x4 __attribute__((ext_vector_type(4)));
typedef unsigned short u16x4 __attribute__((ext_vector_type(4)));

__device__ __forceinline__ short f2bf(float f) {
  unsigned u = __builtin_bit_cast(unsigned, f);
  unsigned r = (u + 0x7fffu + ((u >> 16) & 1u)) >> 16;
  return (short)r;
}
__device__ __forceinline__ float bf2f(short s) {
  unsigned u = ((unsigned)(unsigned short)s) << 16;
  return __builtin_bit_cast(float, u);
}
__device__ __forceinline__ float bflo(unsigned p) {
  return __builtin_bit_cast(float, p << 16);
}
__device__ __forceinline__ float bfhi(unsigned p) {
  return __builtin_bit_cast(float, p & 0xffff0000u);
}
__device__ __forceinline__ float sig_(float x) {
  return __builtin_amdgcn_rcpf(1.0f + __builtin_amdgcn_exp2f(-1.44269504f * x));
}
__device__ __forceinline__ float tanh_(float x) {
  float e = __builtin_amdgcn_exp2f(2.88539008f * x);  // exp(2x)
  return 1.0f - 2.0f * __builtin_amdgcn_rcpf(e + 1.0f);
}

// Pack w_hh [1024][256] fp32 -> bf16 B-fragments in exact MFMA operand order:
// frag (jt,kt): lane holds W[n = jt*16 + (lane&15)][k = kt*32 + (lane>>4)*8 + 0..7]
__global__ void pack_w(const float* __restrict__ w_hh, short* __restrict__ wp) {
  int idx = blockIdx.x * 256 + threadIdx.x;   // 64 jt * 8 kt * 64 lanes
  int lane = idx & 63;
  int kt = (idx >> 6) & 7;
  int jt = idx >> 9;
  int n = jt * 16 + (lane & 15);
  int k0 = kt * 32 + (lane >> 4) * 8;
  bf16x8 v;
#pragma unroll
  for (int j = 0; j < 8; ++j) v[j] = f2bf(w_hh[n * 256 + k0 + j]);
  *(bf16x8*)(wp + (long)idx * 8) = v;
}

__global__ __launch_bounds__(NTHR, 2)
void lstm_main(const float* __restrict__ cd, const float* __restrict__ pred,
               const float* __restrict__ w_ih, const float* __restrict__ b_ih,
               const float* __restrict__ b_hh, const float* __restrict__ w_out,
               const float* __restrict__ b_out, const short* __restrict__ wp,
               float* __restrict__ out) {
  // LDS: weights 128 KB (o-gate, 16 tiles) + h dbuf 16.5 KB + x 8 KB = 152.5 KB
  __shared__ __align__(16) short lds_w[16 * 8 * 64 * 8];
  __shared__ __align__(16) short h_s[2 * HBUF];
  __shared__ __align__(16) short x_s[TT * BT];

  const int tid = threadIdx.x;
  const int lane = tid & 63;
  const int wv = tid >> 6;        // wave 0..7
  const int r0 = blockIdx.x * BT;
  const int lm = lane & 15;
  const int lq = lane >> 4;
  const int m0 = lq * 4;

  const bf16x8* wpf = (const bf16x8*)wp;
  bf16x8* ldsw = (bf16x8*)lds_w;

  // ---- one-time staging ----
  for (int i = tid; i < BT * CONDL; i += NTHR) {
    int r = i / CONDL, t = i % CONDL;
    x_s[t * BT + r] = f2bf(cd[(r0 + r) * CONDL + t]);
  }
  for (int i = tid; i < BT * PREDL; i += NTHR) {
    int r = i / PREDL, t = i % PREDL;
    x_s[(CONDL + t) * BT + r] = f2bf(pred[(r0 + r) * PREDL + t]);
  }
  for (int i = tid; i < HBUF; i += NTHR) h_s[i] = 0;  // h_0 = 0, buffer 0

  // wave wv owns unit-subtiles s0 = wv*2 + {0,1}; jt = g*16 + subtile, g = gate.
  // g in {0,1,2} (i,f,g) -> VGPR; g == 3 (o) -> LDS.
  // LDS o-tile for subtile st lives at frag ((st)*8+kt)*64+lane.
#pragma unroll
  for (int i = 0; i < 2; ++i) {
    int st = wv * 2 + i;
#pragma unroll
    for (int kt = 0; kt < 8; ++kt)
      ldsw[(st * 8 + kt) * 64 + lane] = wpf[((48 + st) * 8 + kt) * 64 + lane];
  }

  // VGPR-resident tiles: 6 per wave (a = g*2+i, g<3) = 48 frags = 192 VGPRs
  bf16x8 wreg[48];
#pragma unroll
  for (int a = 0; a < 6; ++a) {
    int jt = (a >> 1) * 16 + wv * 2 + (a & 1);
#pragma unroll
    for (int kt = 0; kt < 8; ++kt)
      wreg[a * 8 + kt] = wpf[(jt * 8 + kt) * 64 + lane];
  }
#pragma unroll
  for (int i = 0; i < 48; ++i) asm volatile("" : "+v"(wreg[i]));

  // packed (w_ih, b_ih+b_hh) bf16 pairs; index a2 = g*2+i, g in 0..3
  unsigned wbs[8];
#pragma unroll
  for (int a = 0; a < 8; ++a) {
    int j = (a >> 1) * 256 + (wv * 2 + (a & 1)) * 16 + lm;
    unsigned lo = (unsigned short)f2bf(w_ih[j]);
    unsigned hi = (unsigned short)f2bf(b_ih[j] + b_hh[j]);
    wbs[a] = lo | (hi << 16);
  }

  float cst[8];   // cell state: subtile i (2) x batch row v (4)
#pragma unroll
  for (int i = 0; i < 8; ++i) cst[i] = 0.f;

  f32x4 zero4;
  zero4[0] = 0.f; zero4[1] = 0.f; zero4[2] = 0.f; zero4[3] = 0.f;

  __syncthreads();

  // ---- recurrence ----
  for (int t = 0; t < TT; ++t) {
    const short* hr = h_s + (t & 1) * HBUF;
    short* hw = h_s + ((t + 1) & 1) * HBUF;

    f32x4 acc[8];   // chains: a = g*2+i, g=0..3
#pragma unroll
    for (int kt = 0; kt < 8; ++kt) {
      bf16x8 af = *(const bf16x8*)(hr + lm * HPAD + kt * 32 + lq * 8);
#pragma unroll
      for (int a = 0; a < 8; ++a) {
        bf16x8 wf = (a < 6) ? wreg[a * 8 + kt]
                            : ldsw[((wv * 2 + (a & 1)) * 8 + kt) * 64 + lane];
        acc[a] = __builtin_amdgcn_mfma_f32_16x16x32_bf16(
            af, wf, (kt == 0) ? zero4 : acc[a], 0, 0, 0);
      }
    }

    // x_t for this lane's 4 batch rows
    u16x4 xq = *(const u16x4*)(x_s + t * BT + m0);
    float xr[4];
#pragma unroll
    for (int v = 0; v < 4; ++v) xr[v] = bf2f((short)xq[v]);

    // LSTM elementwise; unit u = (wv*2+i)*16 + lm
#pragma unroll
    for (int i = 0; i < 2; ++i) {
      int u = (wv * 2 + i) * 16 + lm;
      float wI = bflo(wbs[i]),     bI = bfhi(wbs[i]);
      float wF = bflo(wbs[2 + i]), bF = bfhi(wbs[2 + i]);
      float wG = bflo(wbs[4 + i]), bG = bfhi(wbs[4 + i]);
      float wO = bflo(wbs[6 + i]), bO = bfhi(wbs[6 + i]);
#pragma unroll
      for (int v = 0; v < 4; ++v) {
        float ig = sig_(acc[i][v]     + xr[v] * wI + bI);
        float fg = sig_(acc[2 + i][v] + xr[v] * wF + bF);
        float gg = tanh_(acc[4 + i][v] + xr[v] * wG + bG);
        float og = sig_(acc[6 + i][v] + xr[v] * wO + bO);
        float cn = fg * cst[i * 4 + v] + ig * gg;
        cst[i * 4 + v] = cn;
        hw[(m0 + v) * HPAD + u] = f2bf(og * tanh_(cn));
      }
    }
    __syncthreads();
  }

  // ---- readout: out[r] = sigmoid(h_last . w_out + b_out); buffer 0 (T even) ----
  const short* hf = h_s;
  float bo = b_out[0];
#pragma unroll
  for (int rr = 0; rr < 2; ++rr) {
    int row = wv * 2 + rr;
    float p = 0.f;
#pragma unroll
    for (int c = 0; c < 4; ++c) {
      int k = lane + c * 64;
      p += bf2f(hf[row * HPAD + k]) * w_out[k];
    }
#pragma unroll
    for (int off = 32; off > 0; off >>= 1) p += __shfl_down(p, off);
    if (lane == 0) out[r0 + row] = sig_(p + bo);
  }
}

extern "C" void kernel_launch(void* const* d_in, const int* in_sizes, int n_in,
                              void* d_out, int out_size, void* d_ws, size_t ws_size,
                              hipStream_t stream) {
  const float* cd    = (const float*)d_in[0];
  const float* pr    = (const float*)d_in[1];
  const float* w_ih  = (const float*)d_in[2];
  const float* w_hh  = (const float*)d_in[3];
  const float* b_ih  = (const float*)d_in[4];
  const float* b_hh  = (const float*)d_in[5];
  const float* w_out = (const float*)d_in[6];
  const float* b_out = (const float*)d_in[7];
  float* out = (float*)d_out;
  short* wp = (short*)d_ws;   // 512 KB packed bf16 weights

  pack_w<<<128, 256, 0, stream>>>(w_hh, wp);
  lstm_main<<<256, NTHR, 0, stream>>>(cd, pr, w_ih, b_ih, b_hh, w_out, b_out, wp, out);
}